// Round 7
// baseline (288.183 us; speedup 1.0000x reference)
//
#include <hip/hip_runtime.h>
#include <hip/hip_bf16.h>

// ---- problem constants (B=4, T=4096, D=1024, SPAN=128) ----
#define BB 4
#define TT 4096
#define DD 1024
#define SS 128
#define MM (BB*TT)       // 16384 rows

typedef __attribute__((ext_vector_type(8))) short bf16x8;
typedef __attribute__((ext_vector_type(4))) short s16x4;
typedef __attribute__((ext_vector_type(4))) float f32x4;

// counted vmem wait: lets N newest vmem ops stay in flight (in-order retire)
#define VMCNT(N) asm volatile("s_waitcnt vmcnt(" #N ")" ::: "memory")
#define LGKM0()  asm volatile("s_waitcnt lgkmcnt(0)" ::: "memory")

__device__ __forceinline__ void block_sync() {
    asm volatile("" ::: "memory");
    __builtin_amdgcn_s_barrier();
    asm volatile("" ::: "memory");
}

__device__ __forceinline__ short f2bf(float f) {
    union { float f; unsigned u; } cv; cv.f = f;
    unsigned u = cv.u;
    u += 0x7fffu + ((u >> 16) & 1u);   // RNE
    return (short)(u >> 16);
}

// direct global->LDS DMA, 16B/lane. Contract: LDS dest = wave-uniform
// base + lane*16 (verified for every call site below).
__device__ __forceinline__ void gload16(const short* g, short* l) {
    __builtin_amdgcn_global_load_lds(
        (const __attribute__((address_space(1))) void*)g,
        (__attribute__((address_space(3))) void*)l, 16, 0, 0);
}

// ============================================================
// K0a: x fp32 -> bf16
// ============================================================
__global__ __launch_bounds__(256) void cast_f32_bf16(
    const float* __restrict__ src, short* __restrict__ dst)
{
    const int i = (blockIdx.x * 256 + threadIdx.x) * 4;
    const float4 v = *(const float4*)(src + i);
    s16x4 o;
    o.x = f2bf(v.x); o.y = f2bf(v.y); o.z = f2bf(v.z); o.w = f2bf(v.w);
    *(s16x4*)(dst + i) = o;
}

// K0b: three weight matrices, one launch (dst contiguous [3][1024][1024])
__global__ __launch_bounds__(256) void cast_w3(
    const float* __restrict__ a, const float* __restrict__ b,
    const float* __restrict__ c, short* __restrict__ dst)
{
    const float* src = (blockIdx.y == 0) ? a : (blockIdx.y == 1) ? b : c;
    short* d = dst + (size_t)blockIdx.y * DD * DD;
    const int i = (blockIdx.x * 256 + threadIdx.x) * 4;
    const float4 v = *(const float4*)(src + i);
    s16x4 o;
    o.x = f2bf(v.x); o.y = f2bf(v.y); o.z = f2bf(v.z); o.w = f2bf(v.w);
    *(s16x4*)(d + i) = o;
}

// ============================================================
// K1: 256x256 8-phase GEMM.  Round-7: decode REVERTED to the round-5
// bijective XCD swizzle (verified 125-128 us).  Round-6's
// XCD-rectangular decode cut FETCH 203->74 MB but cost +30% time:
// co-resident blocks per XCD spanned ~8 W panels + X panel (~8 MB)
// vs 4 MB L2 -> stage-path latency churn.  L2-miss BYTES were not
// the constraint; stage latency stability is.  Core unchanged.
// ============================================================

#define MF(a_, b_, c_) ((GRP == 2)                                            \
    ? __builtin_amdgcn_mfma_f32_16x16x32_bf16((b_), (a_), (c_), 0, 0, 0)      \
    : __builtin_amdgcn_mfma_f32_16x16x32_bf16((a_), (b_), (c_), 0, 0, 0))

#define QKV_PHASE(ABASE, P, STAGE_STMT, VM_STMT)                              \
  do {                                                                        \
    bf16x8 af0k0 = *(const bf16x8*)((ABASE) + (((P)*2)*16   + c16) * 64 + sw0);\
    bf16x8 af0k1 = *(const bf16x8*)((ABASE) + (((P)*2)*16   + c16) * 64 + sw1);\
    bf16x8 af1k0 = *(const bf16x8*)((ABASE) + (((P)*2+1)*16 + c16) * 64 + sw0);\
    bf16x8 af1k1 = *(const bf16x8*)((ABASE) + (((P)*2+1)*16 + c16) * 64 + sw1);\
    STAGE_STMT;                                                               \
    block_sync();                                                             \
    LGKM0();                                                                  \
    __builtin_amdgcn_s_setprio(1);                                            \
    _Pragma("unroll")                                                         \
    for (int nj = 0; nj < 4; nj++) {                                          \
      acc[(P)*2][nj]   = MF(af0k0, bf[nj][0], acc[(P)*2][nj]);                \
      acc[(P)*2][nj]   = MF(af0k1, bf[nj][1], acc[(P)*2][nj]);                \
      acc[(P)*2+1][nj] = MF(af1k0, bf[nj][0], acc[(P)*2+1][nj]);              \
      acc[(P)*2+1][nj] = MF(af1k1, bf[nj][1], acc[(P)*2+1][nj]);              \
    }                                                                         \
    __builtin_amdgcn_s_setprio(0);                                            \
    VM_STMT;                                                                  \
    block_sync();                                                             \
  } while (0)

template<int GRP>
__device__ __forceinline__ void qkv_core(
    const short* __restrict__ X, const short* __restrict__ W,
    const float* __restrict__ bias,
    short* __restrict__ Y, short* __restrict__ vT,
    short* lds, const int m_base, const int n_base)
{
    const int tid  = threadIdx.x;
    const int wv   = tid >> 6, lane = tid & 63;
    const int wm   = wv >> 2,  wn   = wv & 3;
    const int quad = lane >> 4, c16 = lane & 15;
    const int swz  = c16 & 7;
    const int sw0  = ((quad)     ^ swz) * 8;
    const int sw1  = ((quad + 4) ^ swz) * 8;

    auto stageA = [&](int k0, int d, int h) {
        short* dst = lds + d * 16384 + h * 8192;
#pragma unroll
        for (int g = 0; g < 2; g++) {
            const int idx = g * 512 + tid;
            const int row = idx >> 3, slot = idx & 7;
            gload16(X + (size_t)(m_base + h * 128 + row) * DD + k0
                      + ((slot ^ (row & 7)) * 8),
                    dst + row * 64 + slot * 8);
        }
    };
    auto stageB = [&](int k0, int d, int h) {
        short* dst = lds + 32768 + d * 16384 + h * 8192;
#pragma unroll
        for (int g = 0; g < 2; g++) {
            const int idx = g * 512 + tid;
            const int row = idx >> 3, slot = idx & 7;
            gload16(W + (size_t)(n_base + h * 128 + row) * DD + k0
                      + ((slot ^ (row & 7)) * 8),
                    dst + row * 64 + slot * 8);
        }
    };

    f32x4 acc[8][4];
#pragma unroll
    for (int i = 0; i < 8; i++)
#pragma unroll
        for (int j = 0; j < 4; j++) acc[i][j] = (f32x4){0.f, 0.f, 0.f, 0.f};

    stageA(0, 0, 0);  stageA(0, 0, 1);
    stageB(0, 0, 0);  stageB(0, 0, 1);
    stageB(64, 1, 0); stageB(64, 1, 1);
    VMCNT(4);
    block_sync();

    const short* Abuf0 = lds + wm * 8192;
    const short* Abuf1 = lds + 16384 + wm * 8192;
    const short* Bbuf0 = lds + 32768 + (wn >> 1) * 8192 + (wn & 1) * 4096;
    const short* Bbuf1 = lds + 49152 + (wn >> 1) * 8192 + (wn & 1) * 4096;

    bf16x8 bf[4][2];

    for (int it = 0; it < 8; ++it) {
        const int k1 = it * 128 + 64;
        const int k2 = it * 128 + 128;
        const int k3 = it * 128 + 192;
        const bool more = (it < 7);

#pragma unroll
        for (int nj = 0; nj < 4; nj++) {
            bf[nj][0] = *(const bf16x8*)(Bbuf0 + (nj * 16 + c16) * 64 + sw0);
            bf[nj][1] = *(const bf16x8*)(Bbuf0 + (nj * 16 + c16) * 64 + sw1);
        }
        QKV_PHASE(Abuf0, 0, stageA(k1, 1, 0), ((void)0));
        QKV_PHASE(Abuf0, 1, stageA(k1, 1, 1), ((void)0));
        QKV_PHASE(Abuf0, 2, if (more) stageB(k2, 0, 0), ((void)0));
        QKV_PHASE(Abuf0, 3, if (more) stageB(k2, 0, 1),
                  if (more) { VMCNT(4); } else { VMCNT(0); });

#pragma unroll
        for (int nj = 0; nj < 4; nj++) {
            bf[nj][0] = *(const bf16x8*)(Bbuf1 + (nj * 16 + c16) * 64 + sw0);
            bf[nj][1] = *(const bf16x8*)(Bbuf1 + (nj * 16 + c16) * 64 + sw1);
        }
        QKV_PHASE(Abuf1, 0, if (more) stageA(k2, 0, 0), ((void)0));
        QKV_PHASE(Abuf1, 1, if (more) stageA(k2, 0, 1), ((void)0));
        QKV_PHASE(Abuf1, 2, if (more) stageB(k3, 1, 0), ((void)0));
        QKV_PHASE(Abuf1, 3, if (more) stageB(k3, 1, 1),
                  if (more) { VMCNT(4); } else { VMCNT(0); });
    }

    if (GRP != 2) {
#pragma unroll
        for (int nj = 0; nj < 4; nj++) {
            const int col = n_base + wn * 64 + nj * 16 + c16;
            const float bc = bias[col];
#pragma unroll
            for (int mi = 0; mi < 8; mi++) {
                const int row = m_base + wm * 128 + mi * 16 + quad * 4;
#pragma unroll
                for (int r = 0; r < 4; r++)
                    Y[(size_t)(row + r) * DD + col] = f2bf(acc[mi][nj][r] + bc);
            }
        }
    } else {
#pragma unroll
        for (int nj = 0; nj < 4; nj++) {
#pragma unroll
            for (int r = 0; r < 4; r++) {
                const int drow = n_base + wn * 64 + nj * 16 + quad * 4 + r;
                const float bc = bias[drow];
#pragma unroll
                for (int mi = 0; mi < 8; mi++) {
                    const int mcol = m_base + wm * 128 + mi * 16 + c16;
                    vT[((size_t)(mcol >> 12) * DD + drow) * TT + (mcol & 4095)]
                        = f2bf(acc[mi][nj][r] + bc);
                }
            }
        }
    }
}

__global__ __launch_bounds__(512, 2) void qkv_gemm8(
    const short* __restrict__ X, const short* __restrict__ W3,
    const float* __restrict__ bq, const float* __restrict__ bk,
    const float* __restrict__ bv,
    short* __restrict__ q, short* __restrict__ k, short* __restrict__ vT)
{
    __shared__ __align__(16) short lds[65536];   // 128 KiB
    const int bid = blockIdx.x;                  // 768 blocks
    const int wg  = (bid & 7) * 96 + (bid >> 3); // round-5 bijective XCD swizzle
    const int mt  = wg & 63;                     // 0..63
    const int cn  = wg >> 6;                     // 0..11
    const int grp = cn >> 2;                     // 0=Q 1=K 2=V
    const int nt  = cn & 3;                      // 0..3
    const int m_base = mt * 256;
    const int n_base = nt * 256;
    if (grp == 0)      qkv_core<0>(X, W3,              bq, q, nullptr, lds, m_base, n_base);
    else if (grp == 1) qkv_core<1>(X, W3 + DD * DD,    bk, k, nullptr, lds, m_base, n_base);
    else               qkv_core<2>(X, W3 + 2 * DD * DD, bv, nullptr, vT, lds, m_base, n_base);
}

// ============================================================
// K2: 192-key window attention — UNCHANGED from round 6 (verified,
// ~85 us; the 25% window-work cut delivered ~1.6x).
// ============================================================
__global__ __launch_bounds__(512, 2) void attn_fused(
    const short* __restrict__ Q,
    const short* __restrict__ Kb,
    const short* __restrict__ VT,    // [B,1024,4096]
    float* __restrict__ O)           // [16384,1024] fp32
{
    __shared__ short lds[74240];     // 148,480 B

    const int l   = blockIdx.x;
    const int xcd = l & 7;
    const int rr  = l >> 3;               // 0..31
    const int n   = xcd * 4 + (rr & 3);   // both qh of one (b,n) on same XCD
    const int qh  = (rr >> 2) & 1;
    const int b   = rr >> 3;

    const int tid  = threadIdx.x;         // 0..511
    const int wv   = tid >> 6, lane = tid & 63;
    const int quad = lane >> 4, c16 = lane & 15;
    const int qt   = wv >> 1;             // q-tile 0..3
    const int kh   = wv & 1;              // phase-1 96-key half
    const int dh   = wv & 1;              // phase-2 d-half

    const int qrow   = b * TT + n * SS + qh * 64;          // first q row
    const int kbase  = b * TT + n * SS - SS + qh * 64;     // key-window row 0
    const int bstart = b * TT;

    // ---------------- phase 1: S = Q.K^T over 192 keys, BK=64, depth-2 ----
    f32x4 acc[6];
#pragma unroll
    for (int j = 0; j < 6; j++) acc[j] = (f32x4){0.f, 0.f, 0.f, 0.f};

    // stage: Q 1 gload/thr + K 3 gloads/thr = 4/thr.  T2: LDS dest linear,
    // global source column pre-swizzled, read side XORs the same key.
    auto stage1 = [&](int kk, int bi) {
        short* qb = lds + bi * 16384;
        short* kb = qb + 4096;
        const int k0 = kk * 64;
        {
            const int row = tid >> 3, slot = tid & 7;
            gload16(Q + (qrow + row) * DD + k0 + ((slot ^ (row & 7)) * 8),
                    qb + row * 64 + slot * 8);
        }
#pragma unroll
        for (int g = 0; g < 3; g++) {
            const int idx = g * 512 + tid;
            const int row = idx >> 3, slot = idx & 7;   // row 0..191
            int grow = kbase + row;
            if (grow < bstart) grow = bstart;   // n==0 pad rows (masked below)
            gload16(Kb + grow * DD + k0 + ((slot ^ (row & 7)) * 8),
                    kb + row * 64 + slot * 8);
        }
    };

    const int sw7 = c16 & 7;   // read-side swizzle key (rows are x*16+c16)

    stage1(0, 0);
    stage1(1, 1);
    for (int kk = 0; kk < 16; kk++) {
        if (kk < 15) { VMCNT(4); } else { VMCNT(0); }   // own stage(kk) landed
        block_sync();                                    // everyone's landed
        if (kk < 14) stage1(kk + 2, (kk + 2) % 3);       // 2 tiles in flight
        const short* qb = lds + (kk % 3) * 16384;
        const short* kb = qb + 4096;
        __builtin_amdgcn_s_setprio(1);
#pragma unroll
        for (int ks = 0; ks < 2; ks++) {
            const int slot = ((ks * 4 + quad) ^ sw7) * 8;
            bf16x8 a = *(const bf16x8*)(qb + (qt * 16 + c16) * 64 + slot);
#pragma unroll
            for (int j = 0; j < 6; j++) {
                bf16x8 bf = *(const bf16x8*)(kb + (kh * 96 + j * 16 + c16) * 64 + slot);
                acc[j] = __builtin_amdgcn_mfma_f32_16x16x32_bf16(a, bf, acc[j], 0, 0, 0);
            }
        }
        __builtin_amdgcn_s_setprio(0);
    }

    block_sync();   // all waves done reading phase-1 bufs (region reused by V)

    // ---- phase-2 prologue issued BEFORE softmax: V loads fly under it ----
    const int tb2 = n * SS - SS + qh * 64;   // abs t of kv-window col 0
    auto stage2 = [&](int s, int bi) {
        short* vb = lds + bi * 16384;
        const int d0  = (s / 3) * 256;
        const int kv0 = (s % 3) * 64;
#pragma unroll
        for (int g = 0; g < 4; g++) {
            const int idx = g * 512 + tid;
            const int row = idx >> 3, slot = idx & 7;   // d-local row 0..255
            int t = tb2 + kv0 + ((slot ^ (row & 7)) * 8);
            if (t < 0) t = 0;                            // n==0 pad keys: P==0
            gload16(VT + (size_t)(b * DD + d0 + row) * TT + t,
                    vb + row * 64 + slot * 8);
        }
    };
    stage2(0, 0);
    stage2(1, 1);

    // ---------------- softmax: cross-wave over 96-key halves ----------------
    short* Pb   = lds + 61440;                    // [64][200]
    float* smax = (float*)(lds + 49152);          // [8 waves][16 rows]
    float* ssum = (float*)(lds + 49408);
    const float scale = 0.03125f;   // 1/sqrt(1024)
    const int   padk  = (n > 0) ? 0 : (SS - qh * 64);   // valid: k_local >= padk
    float mx4[4], sums[4];

#pragma unroll
    for (int r = 0; r < 4; r++) {                 // pass A: mask + local max
        const int ql = qt * 16 + quad * 4 + r;    // local q row 0..63
        float mx = -3.0e38f;
#pragma unroll
        for (int j = 0; j < 6; j++) {
            const int k_local = kh * 96 + j * 16 + c16;        // 0..191
            const int rel = k_local - SS - ql;
            const bool valid = (rel <= 0) & (rel > -SS) & (k_local >= padk);
            const float sv = valid ? acc[j][r] * scale : -3.0e38f;
            acc[j][r] = sv;
            mx = fmaxf(mx, sv);
        }
#pragma unroll
        for (int o = 1; o < 16; o <<= 1) mx = fmaxf(mx, __shfl_xor(mx, o));
        mx4[r] = mx;
        if (c16 == 0) smax[(qt * 2 + kh) * 16 + quad * 4 + r] = mx;
    }
    LGKM0(); block_sync();

#pragma unroll
    for (int r = 0; r < 4; r++) {                 // pass B: exp + local sum
        const float M = fmaxf(mx4[r], smax[(qt * 2 + (kh ^ 1)) * 16 + quad * 4 + r]);
        float sm = 0.f;
#pragma unroll
        for (int j = 0; j < 6; j++) {
            const float p = __expf(acc[j][r] - M);
            acc[j][r] = p;
            sm += p;
        }
#pragma unroll
        for (int o = 1; o < 16; o <<= 1) sm += __shfl_xor(sm, o);
        sums[r] = sm;
        if (c16 == 0) ssum[(qt * 2 + kh) * 16 + quad * 4 + r] = sm;
    }
    LGKM0(); block_sync();

#pragma unroll
    for (int r = 0; r < 4; r++) {                 // pass C: normalize -> P
        const float inv = 1.0f / (sums[r] + ssum[(qt * 2 + (kh ^ 1)) * 16 + quad * 4 + r]);
#pragma unroll
        for (int j = 0; j < 6; j++)
            Pb[(qt * 16 + quad * 4 + r) * 200 + kh * 96 + j * 16 + c16] = f2bf(acc[j][r] * inv);
    }
    LGKM0();    // P writes retired before the next barrier releases readers

    // -------- phase 2: O = P.V, 12 steps of V[256 d][64 t], depth-2 --------
    f32x4 o_all[32];                 // 4 d-groups x 8 jj
#pragma unroll
    for (int j = 0; j < 32; j++) o_all[j] = (f32x4){0.f, 0.f, 0.f, 0.f};

#pragma unroll
    for (int s = 0; s < 12; s++) {
        if (s < 11) { VMCNT(4); } else { VMCNT(0); }   // own stage(s) landed
        block_sync();                                   // all landed; P visible (s=0)
        if (s < 10) stage2(s + 2, (s + 2) % 3);
        const short* vb = lds + (s % 3) * 16384;
        const int kv0 = (s % 3) * 64;
        const int od  = (s / 3) * 8;                    // 0..24, static after unroll
        __builtin_amdgcn_s_setprio(1);
#pragma unroll
        for (int kc = 0; kc < 2; kc++) {
            bf16x8 a = *(const bf16x8*)(Pb + (qt * 16 + c16) * 200 + kv0 + kc * 32 + quad * 8);
#pragma unroll
            for (int jj = 0; jj < 8; jj++) {
                bf16x8 bvf = *(const bf16x8*)(vb + (dh * 128 + jj * 16 + c16) * 64
                                              + (((kc * 4 + quad) ^ sw7) * 8));
                o_all[od + jj] = __builtin_amdgcn_mfma_f32_16x16x32_bf16(a, bvf, o_all[od + jj], 0, 0, 0);
            }
        }
        __builtin_amdgcn_s_setprio(0);
    }

    // ---- epilogue: coalesced O stores, once (4 d-groups x 8 jj) ----
#pragma unroll
    for (int g8 = 0; g8 < 4; g8++)
#pragma unroll
        for (int jj = 0; jj < 8; jj++)
#pragma unroll
            for (int r = 0; r < 4; r++)
                O[(size_t)(qrow + qt * 16 + quad * 4 + r) * DD
                  + g8 * 256 + dh * 128 + jj * 16 + c16] = o_all[g8 * 8 + jj][r];
}

// ============================================================
extern "C" void kernel_launch(void* const* d_in, const int* in_sizes, int n_in,
                              void* d_out, int out_size, void* d_ws, size_t ws_size,
                              hipStream_t stream) {
    const float* x  = (const float*)d_in[0];
    const float* Wq = (const float*)d_in[1];
    const float* bq = (const float*)d_in[2];
    const float* Wk = (const float*)d_in[3];
    const float* bk = (const float*)d_in[4];
    const float* Wv = (const float*)d_in[5];
    const float* bv = (const float*)d_in[6];
    float* out = (float*)d_out;

    char* ws = (char*)d_ws;
    const size_t SZ = (size_t)MM * DD * 2;     // 33,554,432 B
    short* q   = (short*)(ws);
    short* k   = (short*)(ws + SZ);
    short* vT  = (short*)(ws + 2 * SZ);
    short* xb  = (short*)(ws + 3 * SZ);
    short* w3b = (short*)(ws + 4 * SZ);        // [3][1024][1024] contiguous

    dim3 blk(256);
    cast_f32_bf16<<<MM * DD / 1024, blk, 0, stream>>>(x, xb);
    cast_w3<<<dim3(DD * DD / 1024, 3), blk, 0, stream>>>(Wq, Wk, Wv, w3b);

    qkv_gemm8<<<768, 512, 0, stream>>>(xb, w3b, bq, bk, bv, q, k, vT);

    attn_fused<<<256, 512, 0, stream>>>(q, k, vT, out);
}

// Round 8
// 264.078 us; speedup vs baseline: 1.0913x; 1.0913x over previous
//
#include <hip/hip_runtime.h>
#include <hip/hip_bf16.h>

// ---- problem constants (B=4, T=4096, D=1024, SPAN=128) ----
#define BB 4
#define TT 4096
#define DD 1024
#define SS 128
#define MM (BB*TT)       // 16384 rows

typedef __attribute__((ext_vector_type(8))) short bf16x8;
typedef __attribute__((ext_vector_type(4))) short s16x4;
typedef __attribute__((ext_vector_type(4))) float f32x4;

// counted vmem wait: lets N newest vmem ops stay in flight (in-order retire)
#define VMCNT(N) asm volatile("s_waitcnt vmcnt(" #N ")" ::: "memory")
#define LGKM0()  asm volatile("s_waitcnt lgkmcnt(0)" ::: "memory")

__device__ __forceinline__ void block_sync() {
    asm volatile("" ::: "memory");
    __builtin_amdgcn_s_barrier();
    asm volatile("" ::: "memory");
}

__device__ __forceinline__ short f2bf(float f) {
    union { float f; unsigned u; } cv; cv.f = f;
    unsigned u = cv.u;
    u += 0x7fffu + ((u >> 16) & 1u);   // RNE
    return (short)(u >> 16);
}

// direct global->LDS DMA, 16B/lane. Contract: LDS dest = wave-uniform
// base + lane*16 (verified for every call site below).
__device__ __forceinline__ void gload16(const short* g, short* l) {
    __builtin_amdgcn_global_load_lds(
        (const __attribute__((address_space(1))) void*)g,
        (__attribute__((address_space(3))) void*)l, 16, 0, 0);
}

// ============================================================
// K0 (round-8): both casts in ONE launch (saves a stream-serialization
// boundary).  bid < 16384: x fp32->bf16; else the three weight mats.
// ============================================================
__global__ __launch_bounds__(256) void cast_all(
    const float* __restrict__ x, const float* __restrict__ wq,
    const float* __restrict__ wk, const float* __restrict__ wv,
    short* __restrict__ xb, short* __restrict__ w3b)
{
    const int bid = blockIdx.x;
    const float* src; short* dst; int i;
    if (bid < 16384) {
        src = x; dst = xb;
        i = bid * 1024 + threadIdx.x * 4;
    } else {
        const int b2 = bid - 16384;          // 0..3071 (1024 blocks/matrix)
        const int m  = b2 >> 10;             // 0=Q 1=K 2=V
        src = (m == 0) ? wq : (m == 1) ? wk : wv;
        dst = w3b + (size_t)m * DD * DD;
        i = (b2 & 1023) * 1024 + threadIdx.x * 4;
    }
    const float4 v = *(const float4*)(src + i);
    s16x4 o;
    o.x = f2bf(v.x); o.y = f2bf(v.y); o.z = f2bf(v.z); o.w = f2bf(v.w);
    *(s16x4*)(dst + i) = o;
}

// ============================================================
// K1: 256x256 8-phase GEMM.  Round-8 change: EPILOGUE ONLY — LDS-bounce
// store.  Old epilogue wrote column-strided 32 B fragments (2 KB row
// stride) -> WRITE_SIZE 162-196 MB vs 96 MB ideal (partial-line
// eviction / write-allocate RMW).  New: stage acc+bias into the (dead,
// exactly 128 KB) LDS as the full 256x256 bf16 tile, barrier, then
// fully-linear 16 B/lane stores — every HBM line written whole, once.
// Same values, same order -> bitwise-identical output.  Main loop and
// round-5 decode unchanged (verified control).
// ============================================================

#define MF(a_, b_, c_) ((GRP == 2)                                            \
    ? __builtin_amdgcn_mfma_f32_16x16x32_bf16((b_), (a_), (c_), 0, 0, 0)      \
    : __builtin_amdgcn_mfma_f32_16x16x32_bf16((a_), (b_), (c_), 0, 0, 0))

#define QKV_PHASE(ABASE, P, STAGE_STMT, VM_STMT)                              \
  do {                                                                        \
    bf16x8 af0k0 = *(const bf16x8*)((ABASE) + (((P)*2)*16   + c16) * 64 + sw0);\
    bf16x8 af0k1 = *(const bf16x8*)((ABASE) + (((P)*2)*16   + c16) * 64 + sw1);\
    bf16x8 af1k0 = *(const bf16x8*)((ABASE) + (((P)*2+1)*16 + c16) * 64 + sw0);\
    bf16x8 af1k1 = *(const bf16x8*)((ABASE) + (((P)*2+1)*16 + c16) * 64 + sw1);\
    STAGE_STMT;                                                               \
    block_sync();                                                             \
    LGKM0();                                                                  \
    __builtin_amdgcn_s_setprio(1);                                            \
    _Pragma("unroll")                                                         \
    for (int nj = 0; nj < 4; nj++) {                                          \
      acc[(P)*2][nj]   = MF(af0k0, bf[nj][0], acc[(P)*2][nj]);                \
      acc[(P)*2][nj]   = MF(af0k1, bf[nj][1], acc[(P)*2][nj]);                \
      acc[(P)*2+1][nj] = MF(af1k0, bf[nj][0], acc[(P)*2+1][nj]);              \
      acc[(P)*2+1][nj] = MF(af1k1, bf[nj][1], acc[(P)*2+1][nj]);              \
    }                                                                         \
    __builtin_amdgcn_s_setprio(0);                                            \
    VM_STMT;                                                                  \
    block_sync();                                                             \
  } while (0)

template<int GRP>
__device__ __forceinline__ void qkv_core(
    const short* __restrict__ X, const short* __restrict__ W,
    const float* __restrict__ bias,
    short* __restrict__ Y, short* __restrict__ vT,
    short* lds, const int m_base, const int n_base)
{
    const int tid  = threadIdx.x;
    const int wv   = tid >> 6, lane = tid & 63;
    const int wm   = wv >> 2,  wn   = wv & 3;
    const int quad = lane >> 4, c16 = lane & 15;
    const int swz  = c16 & 7;
    const int sw0  = ((quad)     ^ swz) * 8;
    const int sw1  = ((quad + 4) ^ swz) * 8;

    auto stageA = [&](int k0, int d, int h) {
        short* dst = lds + d * 16384 + h * 8192;
#pragma unroll
        for (int g = 0; g < 2; g++) {
            const int idx = g * 512 + tid;
            const int row = idx >> 3, slot = idx & 7;
            gload16(X + (size_t)(m_base + h * 128 + row) * DD + k0
                      + ((slot ^ (row & 7)) * 8),
                    dst + row * 64 + slot * 8);
        }
    };
    auto stageB = [&](int k0, int d, int h) {
        short* dst = lds + 32768 + d * 16384 + h * 8192;
#pragma unroll
        for (int g = 0; g < 2; g++) {
            const int idx = g * 512 + tid;
            const int row = idx >> 3, slot = idx & 7;
            gload16(W + (size_t)(n_base + h * 128 + row) * DD + k0
                      + ((slot ^ (row & 7)) * 8),
                    dst + row * 64 + slot * 8);
        }
    };

    f32x4 acc[8][4];
#pragma unroll
    for (int i = 0; i < 8; i++)
#pragma unroll
        for (int j = 0; j < 4; j++) acc[i][j] = (f32x4){0.f, 0.f, 0.f, 0.f};

    stageA(0, 0, 0);  stageA(0, 0, 1);
    stageB(0, 0, 0);  stageB(0, 0, 1);
    stageB(64, 1, 0); stageB(64, 1, 1);
    VMCNT(4);
    block_sync();

    const short* Abuf0 = lds + wm * 8192;
    const short* Abuf1 = lds + 16384 + wm * 8192;
    const short* Bbuf0 = lds + 32768 + (wn >> 1) * 8192 + (wn & 1) * 4096;
    const short* Bbuf1 = lds + 49152 + (wn >> 1) * 8192 + (wn & 1) * 4096;

    bf16x8 bf[4][2];

    for (int it = 0; it < 8; ++it) {
        const int k1 = it * 128 + 64;
        const int k2 = it * 128 + 128;
        const int k3 = it * 128 + 192;
        const bool more = (it < 7);

#pragma unroll
        for (int nj = 0; nj < 4; nj++) {
            bf[nj][0] = *(const bf16x8*)(Bbuf0 + (nj * 16 + c16) * 64 + sw0);
            bf[nj][1] = *(const bf16x8*)(Bbuf0 + (nj * 16 + c16) * 64 + sw1);
        }
        QKV_PHASE(Abuf0, 0, stageA(k1, 1, 0), ((void)0));
        QKV_PHASE(Abuf0, 1, stageA(k1, 1, 1), ((void)0));
        QKV_PHASE(Abuf0, 2, if (more) stageB(k2, 0, 0), ((void)0));
        QKV_PHASE(Abuf0, 3, if (more) stageB(k2, 0, 1),
                  if (more) { VMCNT(4); } else { VMCNT(0); });

#pragma unroll
        for (int nj = 0; nj < 4; nj++) {
            bf[nj][0] = *(const bf16x8*)(Bbuf1 + (nj * 16 + c16) * 64 + sw0);
            bf[nj][1] = *(const bf16x8*)(Bbuf1 + (nj * 16 + c16) * 64 + sw1);
        }
        QKV_PHASE(Abuf1, 0, if (more) stageA(k2, 0, 0), ((void)0));
        QKV_PHASE(Abuf1, 1, if (more) stageA(k2, 0, 1), ((void)0));
        QKV_PHASE(Abuf1, 2, if (more) stageB(k3, 1, 0), ((void)0));
        QKV_PHASE(Abuf1, 3, if (more) stageB(k3, 1, 1),
                  if (more) { VMCNT(4); } else { VMCNT(0); });
    }

    // ---- epilogue: LDS-bounce -> fully-coalesced 16 B/lane stores ----
    // Main loop's final phase ended with VMCNT(0)+block_sync: LDS dead,
    // 65536 shorts = exactly one 256x256 bf16 tile.
    if (GRP != 2) {
#pragma unroll
        for (int nj = 0; nj < 4; nj++) {
            const int col = wn * 64 + nj * 16 + c16;            // tile-local
            const float bc = bias[n_base + col];
#pragma unroll
            for (int mi = 0; mi < 8; mi++) {
                const int row = wm * 128 + mi * 16 + quad * 4;  // tile-local
#pragma unroll
                for (int r = 0; r < 4; r++)
                    lds[(row + r) * 256 + col] = f2bf(acc[mi][nj][r] + bc);
            }
        }
        LGKM0(); block_sync();
#pragma unroll
        for (int g = 0; g < 16; g++) {
            const int idx = g * 512 + tid;                      // 0..8191
            const int row = idx >> 5, ch = idx & 31;            // 32x16B per row
            *(bf16x8*)(Y + (size_t)(m_base + row) * DD + n_base + ch * 8)
                = *(const bf16x8*)(lds + row * 256 + ch * 8);
        }
    } else {
        // operand-swapped acc = C^T: LDS tile is [256 drow][256 tcol]
        const int b  = m_base >> 12;
        const int t0 = m_base & 4095;
#pragma unroll
        for (int nj = 0; nj < 4; nj++) {
#pragma unroll
            for (int r = 0; r < 4; r++) {
                const int drow = wn * 64 + nj * 16 + quad * 4 + r;   // tile-local
                const float bc = bias[n_base + drow];
#pragma unroll
                for (int mi = 0; mi < 8; mi++) {
                    const int tcol = wm * 128 + mi * 16 + c16;       // tile-local
                    lds[drow * 256 + tcol] = f2bf(acc[mi][nj][r] + bc);
                }
            }
        }
        LGKM0(); block_sync();
#pragma unroll
        for (int g = 0; g < 16; g++) {
            const int idx = g * 512 + tid;
            const int row = idx >> 5, ch = idx & 31;
            *(bf16x8*)(vT + ((size_t)b * DD + n_base + row) * TT + t0 + ch * 8)
                = *(const bf16x8*)(lds + row * 256 + ch * 8);
        }
    }
}

__global__ __launch_bounds__(512, 2) void qkv_gemm8(
    const short* __restrict__ X, const short* __restrict__ W3,
    const float* __restrict__ bq, const float* __restrict__ bk,
    const float* __restrict__ bv,
    short* __restrict__ q, short* __restrict__ k, short* __restrict__ vT)
{
    __shared__ __align__(16) short lds[65536];   // 128 KiB
    const int bid = blockIdx.x;                  // 768 blocks
    const int wg  = (bid & 7) * 96 + (bid >> 3); // round-5 bijective XCD swizzle
    const int mt  = wg & 63;                     // 0..63
    const int cn  = wg >> 6;                     // 0..11
    const int grp = cn >> 2;                     // 0=Q 1=K 2=V
    const int nt  = cn & 3;                      // 0..3
    const int m_base = mt * 256;
    const int n_base = nt * 256;
    if (grp == 0)      qkv_core<0>(X, W3,              bq, q, nullptr, lds, m_base, n_base);
    else if (grp == 1) qkv_core<1>(X, W3 + DD * DD,    bk, k, nullptr, lds, m_base, n_base);
    else               qkv_core<2>(X, W3 + 2 * DD * DD, bv, nullptr, vT, lds, m_base, n_base);
}

// ============================================================
// K2: 192-key window attention — UNCHANGED from round 6 (verified).
// ============================================================
__global__ __launch_bounds__(512, 2) void attn_fused(
    const short* __restrict__ Q,
    const short* __restrict__ Kb,
    const short* __restrict__ VT,    // [B,1024,4096]
    float* __restrict__ O)           // [16384,1024] fp32
{
    __shared__ short lds[74240];     // 148,480 B

    const int l   = blockIdx.x;
    const int xcd = l & 7;
    const int rr  = l >> 3;               // 0..31
    const int n   = xcd * 4 + (rr & 3);   // both qh of one (b,n) on same XCD
    const int qh  = (rr >> 2) & 1;
    const int b   = rr >> 3;

    const int tid  = threadIdx.x;         // 0..511
    const int wv   = tid >> 6, lane = tid & 63;
    const int quad = lane >> 4, c16 = lane & 15;
    const int qt   = wv >> 1;             // q-tile 0..3
    const int kh   = wv & 1;              // phase-1 96-key half
    const int dh   = wv & 1;              // phase-2 d-half

    const int qrow   = b * TT + n * SS + qh * 64;          // first q row
    const int kbase  = b * TT + n * SS - SS + qh * 64;     // key-window row 0
    const int bstart = b * TT;

    // ---------------- phase 1: S = Q.K^T over 192 keys, BK=64, depth-2 ----
    f32x4 acc[6];
#pragma unroll
    for (int j = 0; j < 6; j++) acc[j] = (f32x4){0.f, 0.f, 0.f, 0.f};

    auto stage1 = [&](int kk, int bi) {
        short* qb = lds + bi * 16384;
        short* kb = qb + 4096;
        const int k0 = kk * 64;
        {
            const int row = tid >> 3, slot = tid & 7;
            gload16(Q + (qrow + row) * DD + k0 + ((slot ^ (row & 7)) * 8),
                    qb + row * 64 + slot * 8);
        }
#pragma unroll
        for (int g = 0; g < 3; g++) {
            const int idx = g * 512 + tid;
            const int row = idx >> 3, slot = idx & 7;   // row 0..191
            int grow = kbase + row;
            if (grow < bstart) grow = bstart;   // n==0 pad rows (masked below)
            gload16(Kb + grow * DD + k0 + ((slot ^ (row & 7)) * 8),
                    kb + row * 64 + slot * 8);
        }
    };

    const int sw7 = c16 & 7;   // read-side swizzle key (rows are x*16+c16)

    stage1(0, 0);
    stage1(1, 1);
    for (int kk = 0; kk < 16; kk++) {
        if (kk < 15) { VMCNT(4); } else { VMCNT(0); }   // own stage(kk) landed
        block_sync();                                    // everyone's landed
        if (kk < 14) stage1(kk + 2, (kk + 2) % 3);       // 2 tiles in flight
        const short* qb = lds + (kk % 3) * 16384;
        const short* kb = qb + 4096;
        __builtin_amdgcn_s_setprio(1);
#pragma unroll
        for (int ks = 0; ks < 2; ks++) {
            const int slot = ((ks * 4 + quad) ^ sw7) * 8;
            bf16x8 a = *(const bf16x8*)(qb + (qt * 16 + c16) * 64 + slot);
#pragma unroll
            for (int j = 0; j < 6; j++) {
                bf16x8 bf = *(const bf16x8*)(kb + (kh * 96 + j * 16 + c16) * 64 + slot);
                acc[j] = __builtin_amdgcn_mfma_f32_16x16x32_bf16(a, bf, acc[j], 0, 0, 0);
            }
        }
        __builtin_amdgcn_s_setprio(0);
    }

    block_sync();   // all waves done reading phase-1 bufs (region reused by V)

    // ---- phase-2 prologue issued BEFORE softmax: V loads fly under it ----
    const int tb2 = n * SS - SS + qh * 64;   // abs t of kv-window col 0
    auto stage2 = [&](int s, int bi) {
        short* vb = lds + bi * 16384;
        const int d0  = (s / 3) * 256;
        const int kv0 = (s % 3) * 64;
#pragma unroll
        for (int g = 0; g < 4; g++) {
            const int idx = g * 512 + tid;
            const int row = idx >> 3, slot = idx & 7;   // d-local row 0..255
            int t = tb2 + kv0 + ((slot ^ (row & 7)) * 8);
            if (t < 0) t = 0;                            // n==0 pad keys: P==0
            gload16(VT + (size_t)(b * DD + d0 + row) * TT + t,
                    vb + row * 64 + slot * 8);
        }
    };
    stage2(0, 0);
    stage2(1, 1);

    // ---------------- softmax: cross-wave over 96-key halves ----------------
    short* Pb   = lds + 61440;                    // [64][200]
    float* smax = (float*)(lds + 49152);          // [8 waves][16 rows]
    float* ssum = (float*)(lds + 49408);
    const float scale = 0.03125f;   // 1/sqrt(1024)
    const int   padk  = (n > 0) ? 0 : (SS - qh * 64);   // valid: k_local >= padk
    float mx4[4], sums[4];

#pragma unroll
    for (int r = 0; r < 4; r++) {                 // pass A: mask + local max
        const int ql = qt * 16 + quad * 4 + r;    // local q row 0..63
        float mx = -3.0e38f;
#pragma unroll
        for (int j = 0; j < 6; j++) {
            const int k_local = kh * 96 + j * 16 + c16;        // 0..191
            const int rel = k_local - SS - ql;
            const bool valid = (rel <= 0) & (rel > -SS) & (k_local >= padk);
            const float sv = valid ? acc[j][r] * scale : -3.0e38f;
            acc[j][r] = sv;
            mx = fmaxf(mx, sv);
        }
#pragma unroll
        for (int o = 1; o < 16; o <<= 1) mx = fmaxf(mx, __shfl_xor(mx, o));
        mx4[r] = mx;
        if (c16 == 0) smax[(qt * 2 + kh) * 16 + quad * 4 + r] = mx;
    }
    LGKM0(); block_sync();

#pragma unroll
    for (int r = 0; r < 4; r++) {                 // pass B: exp + local sum
        const float M = fmaxf(mx4[r], smax[(qt * 2 + (kh ^ 1)) * 16 + quad * 4 + r]);
        float sm = 0.f;
#pragma unroll
        for (int j = 0; j < 6; j++) {
            const float p = __expf(acc[j][r] - M);
            acc[j][r] = p;
            sm += p;
        }
#pragma unroll
        for (int o = 1; o < 16; o <<= 1) sm += __shfl_xor(sm, o);
        sums[r] = sm;
        if (c16 == 0) ssum[(qt * 2 + kh) * 16 + quad * 4 + r] = sm;
    }
    LGKM0(); block_sync();

#pragma unroll
    for (int r = 0; r < 4; r++) {                 // pass C: normalize -> P
        const float inv = 1.0f / (sums[r] + ssum[(qt * 2 + (kh ^ 1)) * 16 + quad * 4 + r]);
#pragma unroll
        for (int j = 0; j < 6; j++)
            Pb[(qt * 16 + quad * 4 + r) * 200 + kh * 96 + j * 16 + c16] = f2bf(acc[j][r] * inv);
    }
    LGKM0();    // P writes retired before the next barrier releases readers

    // -------- phase 2: O = P.V, 12 steps of V[256 d][64 t], depth-2 --------
    f32x4 o_all[32];                 // 4 d-groups x 8 jj
#pragma unroll
    for (int j = 0; j < 32; j++) o_all[j] = (f32x4){0.f, 0.f, 0.f, 0.f};

#pragma unroll
    for (int s = 0; s < 12; s++) {
        if (s < 11) { VMCNT(4); } else { VMCNT(0); }   // own stage(s) landed
        block_sync();                                   // all landed; P visible (s=0)
        if (s < 10) stage2(s + 2, (s + 2) % 3);
        const short* vb = lds + (s % 3) * 16384;
        const int kv0 = (s % 3) * 64;
        const int od  = (s / 3) * 8;                    // 0..24, static after unroll
        __builtin_amdgcn_s_setprio(1);
#pragma unroll
        for (int kc = 0; kc < 2; kc++) {
            bf16x8 a = *(const bf16x8*)(Pb + (qt * 16 + c16) * 200 + kv0 + kc * 32 + quad * 8);
#pragma unroll
            for (int jj = 0; jj < 8; jj++) {
                bf16x8 bvf = *(const bf16x8*)(vb + (dh * 128 + jj * 16 + c16) * 64
                                              + (((kc * 4 + quad) ^ sw7) * 8));
                o_all[od + jj] = __builtin_amdgcn_mfma_f32_16x16x32_bf16(a, bvf, o_all[od + jj], 0, 0, 0);
            }
        }
        __builtin_amdgcn_s_setprio(0);
    }

    // ---- epilogue: coalesced O stores, once (4 d-groups x 8 jj) ----
#pragma unroll
    for (int g8 = 0; g8 < 4; g8++)
#pragma unroll
        for (int jj = 0; jj < 8; jj++)
#pragma unroll
            for (int r = 0; r < 4; r++)
                O[(size_t)(qrow + qt * 16 + quad * 4 + r) * DD
                  + g8 * 256 + dh * 128 + jj * 16 + c16] = o_all[g8 * 8 + jj][r];
}

// ============================================================
extern "C" void kernel_launch(void* const* d_in, const int* in_sizes, int n_in,
                              void* d_out, int out_size, void* d_ws, size_t ws_size,
                              hipStream_t stream) {
    const float* x  = (const float*)d_in[0];
    const float* Wq = (const float*)d_in[1];
    const float* bq = (const float*)d_in[2];
    const float* Wk = (const float*)d_in[3];
    const float* bk = (const float*)d_in[4];
    const float* Wv = (const float*)d_in[5];
    const float* bv = (const float*)d_in[6];
    float* out = (float*)d_out;

    char* ws = (char*)d_ws;
    const size_t SZ = (size_t)MM * DD * 2;     // 33,554,432 B
    short* q   = (short*)(ws);
    short* k   = (short*)(ws + SZ);
    short* vT  = (short*)(ws + 2 * SZ);
    short* xb  = (short*)(ws + 3 * SZ);
    short* w3b = (short*)(ws + 4 * SZ);        // [3][1024][1024] contiguous

    dim3 blk(256);
    cast_all<<<16384 + 3072, blk, 0, stream>>>(x, Wq, Wk, Wv, xb, w3b);

    qkv_gemm8<<<768, 512, 0, stream>>>(xb, w3b, bq, bk, bv, q, k, vT);

    attn_fused<<<256, 512, 0, stream>>>(q, k, vT, out);
}